// Round 7
// baseline (146.159 us; speedup 1.0000x reference)
//
#include <hip/hip_runtime.h>
#include <math.h>

#define BB 4
#define NSZ 2048
#define FDIM 128
#define ODIM 32
#define HH 8

typedef short short8 __attribute__((ext_vector_type(8)));
typedef float f32x4 __attribute__((ext_vector_type(4)));

// workspace layout (float units)
#define WS_EAP  0                 // float2[B*H*N] (EA, EA2)   = 131072 floats
#define WS_EBP  131072            // float2[B*H*N] (EB, EB2)   = 131072 floats
#define WS_ADJB 262144            // u32[B*N*64]               = 524288 words
#define WS_WHF  786432            // bf16 Wh B-frags           = 1048576 floats (4MB)
// whf: int4[((b*H+h)*64 + jt)*2 + ot][64 lanes]

// round-to-nearest-even float -> bf16, result in TOP 16 bits
__device__ __forceinline__ unsigned bfbits(float f) {
    unsigned u = __builtin_bit_cast(unsigned, f);
    return u + 0x7fffu + ((u >> 16) & 1u);
}
// dword = (bf16(b) << 16) | bf16(a)
__device__ __forceinline__ unsigned bfpack(float a, float b) {
    return __builtin_amdgcn_perm(bfbits(b), bfbits(a), 0x07060302);
}

// ---------------------------------------------------------------------------
// Fused prep. Blocks [0,16384): adj bitmask pack (HBM stream).
// Blocks [16384,17408): MFMA projection for one (b,h,64 n-rows). W[h] staged
// per-block into padded LDS; Wh B-frags built in-block via LDS transpose.
// ---------------------------------------------------------------------------
__global__ __launch_bounds__(256) void k_prep(const float* __restrict__ x,
                                              const float* __restrict__ adj,
                                              const float* __restrict__ W,
                                              const float* __restrict__ a_src,
                                              const float* __restrict__ a_dst,
                                              unsigned* __restrict__ adjb,
                                              int4* __restrict__ whf,
                                              float2* __restrict__ eap,
                                              float2* __restrict__ ebp) {
    __shared__ float wsl[FDIM * 33];          // W[h] staged, row-padded (k*33+o)
    __shared__ unsigned short wlds[64][33];   // bf16 Wh tile [local n][o], +1 pad
    int t = threadIdx.x;

    if (blockIdx.x < 16384) {
        // ---------------- adj bitmask part ----------------
        int g = blockIdx.x * 256 + t;
        int l = g & 7;
        int word = g >> 3;
        int wk = word & 63;
        int row = word >> 6;
        int i = row & (NSZ - 1);
        const float4 v = *(const float4*)&adj[(size_t)row * NSZ + wk * 32 + l * 4];
        unsigned m = 0;
        if (v.x > 0.f) m |= 1u << (l * 4 + 0);
        if (v.y > 0.f) m |= 1u << (l * 4 + 1);
        if (v.z > 0.f) m |= 1u << (l * 4 + 2);
        if (v.w > 0.f) m |= 1u << (l * 4 + 3);
        m |= (unsigned)__shfl_xor((int)m, 1);
        m |= (unsigned)__shfl_xor((int)m, 2);
        m |= (unsigned)__shfl_xor((int)m, 4);
        if (l == 0) {
            int jb = i - wk * 32;
            if (jb >= 0 && jb < 32) m |= 1u << jb;  // self-loop
            adjb[word] = m;
        }
        return;
    }

    // ---------------- projection part ----------------
    int bidx = blockIdx.x - 16384;              // [0,1024): b(2) h(3) nt(5)
    int b = bidx >> 8;
    int h = (bidx >> 5) & 7;
    int nt = bidx & 31;
    int n0 = nt * 64;
    int w = t >> 6, lane = t & 63;
    int col = lane & 15, quad = lane >> 4;

    // stage W[h] (4096 floats) coalesced into padded LDS
#pragma unroll
    for (int m = 0; m < 16; m++) {
        int idx = t + m * 256;
        wsl[(idx >> 5) * 33 + (idx & 31)] = W[(size_t)h * (FDIM * ODIM) + idx];
    }

    // A-fragments: lane(quad,col) element j = x[b][n0+w*16+col][kt*32+quad*8+j]
    const float* xp = x + ((size_t)(b * NSZ) + n0 + w * 16 + col) * FDIM + quad * 8;
    int4 afr[4];
#pragma unroll
    for (int kt = 0; kt < 4; kt++) {
        float4 xa = *(const float4*)(xp + kt * 32);
        float4 xb = *(const float4*)(xp + kt * 32 + 4);
        afr[kt] = make_int4((int)bfpack(xa.x, xa.y), (int)bfpack(xa.z, xa.w),
                            (int)bfpack(xb.x, xb.y), (int)bfpack(xb.z, xb.w));
    }
    __syncthreads();

    // build W B-frags from LDS and run 8 MFMAs
    f32x4 alo = {0.f, 0.f, 0.f, 0.f};
    f32x4 ahi = {0.f, 0.f, 0.f, 0.f};
#pragma unroll
    for (int kt = 0; kt < 4; kt++) {
        short8 a8 = __builtin_bit_cast(short8, afr[kt]);
#pragma unroll
        for (int ot = 0; ot < 2; ot++) {
            unsigned d[4];
#pragma unroll
            for (int jp = 0; jp < 4; jp++) {
                float lo = wsl[(kt * 32 + quad * 8 + 2 * jp) * 33 + ot * 16 + col];
                float hi = wsl[(kt * 32 + quad * 8 + 2 * jp + 1) * 33 + ot * 16 + col];
                d[jp] = bfpack(lo, hi);
            }
            int4 bf = make_int4((int)d[0], (int)d[1], (int)d[2], (int)d[3]);
            if (ot == 0)
                alo = __builtin_amdgcn_mfma_f32_16x16x32_bf16(a8,
                        __builtin_bit_cast(short8, bf), alo, 0, 0, 0);
            else
                ahi = __builtin_amdgcn_mfma_f32_16x16x32_bf16(a8,
                        __builtin_bit_cast(short8, bf), ahi, 0, 0, 0);
        }
    }

    // alphas: reduce Wh[row]*a over o (col lanes), then exp factors
    float as0 = a_src[h * ODIM + col], as1 = a_src[h * ODIM + 16 + col];
    float ad0 = a_dst[h * ODIM + col], ad1 = a_dst[h * ODIM + 16 + col];
#pragma unroll
    for (int r = 0; r < 4; r++) {
        float pa = alo[r] * as0 + ahi[r] * as1;
        float pb = alo[r] * ad0 + ahi[r] * ad1;
#pragma unroll
        for (int mk = 1; mk <= 8; mk <<= 1) {
            pa += __shfl_xor(pa, mk);
            pb += __shfl_xor(pb, mk);
        }
        if (col == 0) {
            size_t idx = (size_t)(b * HH + h) * NSZ + n0 + w * 16 + quad * 4 + r;
            eap[idx] = make_float2(__expf(pa - 8.f), __expf(0.2f * pa - 8.f));
            ebp[idx] = make_float2(__expf(pb - 8.f), __expf(0.2f * pb - 8.f));
        }
    }

    // Wh -> LDS (bf16), then gather B-fragments: wave w does (jl=w>>1, ot=w&1)
#pragma unroll
    for (int r = 0; r < 4; r++) {
        wlds[w * 16 + quad * 4 + r][col]      = (unsigned short)(bfbits(alo[r]) >> 16);
        wlds[w * 16 + quad * 4 + r][col + 16] = (unsigned short)(bfbits(ahi[r]) >> 16);
    }
    __syncthreads();
    int jl = w >> 1, ot = w & 1;
    unsigned d[4];
#pragma unroll
    for (int jp = 0; jp < 4; jp++) {
        unsigned lo = wlds[jl * 32 + quad * 8 + 2 * jp][ot * 16 + col];
        unsigned hi = wlds[jl * 32 + quad * 8 + 2 * jp + 1][ot * 16 + col];
        d[jp] = (hi << 16) | lo;
    }
    int fragid = ((b * HH + h) * 64 + nt * 2 + jl) * 2 + ot;
    whf[(size_t)fragid * 64 + lane] = make_int4((int)d[0], (int)d[1], (int)d[2], (int)d[3]);
}

// masked p-fragment: 8 j's -> bf16x8 A-frag. Truncating pack (perm of top16);
// mask applied on packed dwords via sign-extended bit masks (pure VALU).
__device__ __forceinline__ int4 pfrag(float eaa, float eab, const float4& l0,
                                      const float4& l1, const float4& l2,
                                      const float4& l3, unsigned word, int shb) {
    float p0 = fmaxf(eaa * l0.x, eab * l0.y);
    float p1 = fmaxf(eaa * l0.z, eab * l0.w);
    float p2 = fmaxf(eaa * l1.x, eab * l1.y);
    float p3 = fmaxf(eaa * l1.z, eab * l1.w);
    float p4 = fmaxf(eaa * l2.x, eab * l2.y);
    float p5 = fmaxf(eaa * l2.z, eab * l2.w);
    float p6 = fmaxf(eaa * l3.x, eab * l3.y);
    float p7 = fmaxf(eaa * l3.z, eab * l3.w);
    unsigned d0 = __builtin_amdgcn_perm(__builtin_bit_cast(unsigned, p1),
                                        __builtin_bit_cast(unsigned, p0), 0x07060302);
    unsigned d1 = __builtin_amdgcn_perm(__builtin_bit_cast(unsigned, p3),
                                        __builtin_bit_cast(unsigned, p2), 0x07060302);
    unsigned d2 = __builtin_amdgcn_perm(__builtin_bit_cast(unsigned, p5),
                                        __builtin_bit_cast(unsigned, p4), 0x07060302);
    unsigned d3 = __builtin_amdgcn_perm(__builtin_bit_cast(unsigned, p7),
                                        __builtin_bit_cast(unsigned, p6), 0x07060302);
    unsigned mk[4];
#pragma unroll
    for (int k = 0; k < 4; k++) {
        int s0 = ((int)(word << (shb - 2 * k))) >> 31;      // bit qsh+2k -> 0/-1
        int s1 = ((int)(word << (shb - 2 * k - 1))) >> 31;  // bit qsh+2k+1
        mk[k] = __builtin_amdgcn_perm((unsigned)s1, (unsigned)s0, 0x07060302);
    }
    return make_int4((int)(d0 & mk[0]), (int)(d1 & mk[1]),
                     (int)(d2 & mk[2]), (int)(d3 & mk[3]));
}

// ---------------------------------------------------------------------------
// Fused masked-softmax aggregation. Block = (b,h,64 i-rows), 4 waves; each
// wave covers ALL 4 i-fragments for a 16-jt quarter of the j range, so every
// eb LDS read and whf B-frag load feeds 12 MFMAs. 4-way combine through the
// reused 24KB LDS buffer; wave 0 epilogue.
// ---------------------------------------------------------------------------
__global__ __launch_bounds__(256, 4) void k_gat(const int4* __restrict__ whf,
                                                const float2* __restrict__ eap,
                                                const float2* __restrict__ ebp,
                                                const unsigned* __restrict__ adjb,
                                                float* __restrict__ out) {
    __shared__ float sbuf[6144];   // [0..4095]: eb table; whole 24KB: combine

    int t = threadIdx.x;
    int u = blockIdx.x;
    int unit = (u & 7) * 128 + (u >> 3);  // XCD swizzle
    int b = unit >> 8;
    int h = (unit >> 5) & 7;
    int i0 = (unit & 31) * 64;
    int wave = t >> 6, lane = t & 63;
    int col = lane & 15, quad = lane >> 4, qsh = quad * 8;
    int shb = 31 - qsh;
    size_t bh = (size_t)(b * HH + h);

    // stage eb table: 4096 floats, coalesced
    const float4* ebg = (const float4*)(ebp + bh * NSZ);
#pragma unroll
    for (int k = 0; k < 4; k++) ((float4*)sbuf)[t + k * 256] = ebg[t + k * 256];

    float2 ea[4];
    const uint4* mp[4];
#pragma unroll
    for (int f = 0; f < 4; f++) {
        ea[f] = eap[bh * NSZ + i0 + f * 16 + col];
        mp[f] = (const uint4*)(adjb + ((size_t)(b * NSZ) + i0 + f * 16 + col) * 64) + wave * 4;
    }
    const int4* bfp = whf + bh * 8192 + lane;

    f32x4 ac[4][3];   // [i-frag][0 = o 0..15, 1 = o 16..31, 2 = den]
#pragma unroll
    for (int f = 0; f < 4; f++)
#pragma unroll
        for (int c = 0; c < 3; c++) ac[f][c] = (f32x4){0.f, 0.f, 0.f, 0.f};
    const int4 onesv = make_int4(0x3F803F80, 0x3F803F80, 0x3F803F80, 0x3F803F80);
    short8 bones = __builtin_bit_cast(short8, onesv);

    __syncthreads();

    for (int jt4 = 0; jt4 < 4; jt4++) {
        uint4 mw[4];
#pragma unroll
        for (int f = 0; f < 4; f++) mw[f] = mp[f][jt4];
#pragma unroll
        for (int q = 0; q < 4; q++) {
            int jt = wave * 16 + jt4 * 4 + q;
            const float4* el = (const float4*)&sbuf[(jt * 32 + qsh) * 2];
            float4 l0 = el[0], l1 = el[1], l2 = el[2], l3 = el[3];
            int4 blo = bfp[jt * 128];
            int4 bhi = bfp[jt * 128 + 64];
            short8 b0 = __builtin_bit_cast(short8, blo);
            short8 b1 = __builtin_bit_cast(short8, bhi);
            unsigned wq[4] = {mw[0].x, mw[1].x, mw[2].x, mw[3].x};
            if (q == 1) { wq[0] = mw[0].y; wq[1] = mw[1].y; wq[2] = mw[2].y; wq[3] = mw[3].y; }
            if (q == 2) { wq[0] = mw[0].z; wq[1] = mw[1].z; wq[2] = mw[2].z; wq[3] = mw[3].z; }
            if (q == 3) { wq[0] = mw[0].w; wq[1] = mw[1].w; wq[2] = mw[2].w; wq[3] = mw[3].w; }
#pragma unroll
            for (int f = 0; f < 4; f++) {
                int4 fr = pfrag(ea[f].x, ea[f].y, l0, l1, l2, l3, wq[f], shb);
                short8 a8 = __builtin_bit_cast(short8, fr);
                ac[f][0] = __builtin_amdgcn_mfma_f32_16x16x32_bf16(a8, b0, ac[f][0], 0, 0, 0);
                ac[f][1] = __builtin_amdgcn_mfma_f32_16x16x32_bf16(a8, b1, ac[f][1], 0, 0, 0);
                ac[f][2] = __builtin_amdgcn_mfma_f32_16x16x32_bf16(a8, bones, ac[f][2], 0, 0, 0);
            }
        }
    }

    // ---- 4-way combine through sbuf (eb table dead now) ----
    f32x4* reg0 = (f32x4*)&sbuf[0];      // 768 f32x4
    f32x4* reg1 = (f32x4*)&sbuf[3072];
    __syncthreads();
    if (wave >= 2) {
        f32x4* rg = (wave == 2) ? reg0 : reg1;
#pragma unroll
        for (int f = 0; f < 4; f++)
#pragma unroll
            for (int c = 0; c < 3; c++) rg[(f * 3 + c) * 64 + lane] = ac[f][c];
    }
    __syncthreads();
    if (wave < 2) {
        f32x4* rg = (wave == 0) ? reg0 : reg1;
#pragma unroll
        for (int f = 0; f < 4; f++)
#pragma unroll
            for (int c = 0; c < 3; c++) {
                f32x4 v = rg[(f * 3 + c) * 64 + lane];
#pragma unroll
                for (int r = 0; r < 4; r++) ac[f][c][r] += v[r];
            }
    }
    __syncthreads();
    if (wave == 1) {
#pragma unroll
        for (int f = 0; f < 4; f++)
#pragma unroll
            for (int c = 0; c < 3; c++) reg0[(f * 3 + c) * 64 + lane] = ac[f][c];
    }
    __syncthreads();
    if (wave != 0) return;
#pragma unroll
    for (int f = 0; f < 4; f++)
#pragma unroll
        for (int c = 0; c < 3; c++) {
            f32x4 v = reg0[(f * 3 + c) * 64 + lane];
#pragma unroll
            for (int r = 0; r < 4; r++) ac[f][c][r] += v[r];
        }

    // epilogue: C/D layout col=lane&15, row=f*16+quad*4+reg; ac[f][2][r] = den
    float* op = out + ((size_t)(b * NSZ) + i0) * (HH * ODIM) + h * ODIM + col;
#pragma unroll
    for (int f = 0; f < 4; f++)
#pragma unroll
        for (int r = 0; r < 4; r++) {
            int row = f * 16 + quad * 4 + r;
            float inv = 1.0f / ac[f][2][r];
            op[(size_t)row * (HH * ODIM)]      = fmaxf(ac[f][0][r] * inv, 0.f);
            op[(size_t)row * (HH * ODIM) + 16] = fmaxf(ac[f][1][r] * inv, 0.f);
        }
}

extern "C" void kernel_launch(void* const* d_in, const int* in_sizes, int n_in,
                              void* d_out, int out_size, void* d_ws, size_t ws_size,
                              hipStream_t stream) {
    const float* x     = (const float*)d_in[0];
    const float* adj   = (const float*)d_in[1];
    const float* W     = (const float*)d_in[2];
    const float* a_src = (const float*)d_in[3];
    const float* a_dst = (const float*)d_in[4];
    float* out = (float*)d_out;

    float* ws = (float*)d_ws;
    float2* eap    = (float2*)(ws + WS_EAP);
    float2* ebp    = (float2*)(ws + WS_EBP);
    unsigned* adjb = (unsigned*)(ws + WS_ADJB);
    int4* whf      = (int4*)(ws + WS_WHF);

    // fused prep: 16384 adj-bitmask blocks + 1024 MFMA-projection blocks
    k_prep<<<dim3(16384 + 1024), dim3(256), 0, stream>>>(x, adj, W, a_src, a_dst,
                                                         adjb, whf, eap, ebp);
    // fused masked softmax + MFMA aggregation: 1024 blocks x 4 waves
    k_gat<<<dim3(BB * HH * (NSZ / 64)), dim3(256), 0, stream>>>(whf, eap, ebp, adjb, out);
}